// Round 2
// baseline (590.707 us; speedup 1.0000x reference)
//
#include <hip/hip_runtime.h>
#include <cstdint>
#include <cstddef>

#define DDIM 4096          // hidden dim
#define D4   1024          // float4 per token row
#define NE   16            // experts
#define KC4  128           // K-chunk in float4 (512 floats)
#define NCHUNK 8           // DDIM / 512
#define SCHUNK 256         // scatter chunk (tokens)

// async 16B global->LDS (lane's data lands at wave-uniform base + lane*16)
__device__ __forceinline__ void load_lds16(const void* g, void* l) {
    __builtin_amdgcn_global_load_lds(
        (const __attribute__((address_space(1))) unsigned int*)g,
        (__attribute__((address_space(3))) unsigned int*)l, 16, 0, 0);
}

__device__ __forceinline__ float dot4(float4 a, float4 w) {
    return a.x * w.x + a.y * w.y + a.z * w.z + a.w * w.w;
}

// ---------------------------------------------------------------------------
// Pass A: logits + top-2 softmax renorm + dispatch + packed pair byte +
// per-256-token-chunk expert histogram + (-1)-fill of this block's slice of
// expert_indices (folded from the old router_fill so its 1 MB write hides
// under the streaming loop).
// Block = 4 waves = 32 tokens. W staged K-chunk-wise into DOUBLE-BUFFERED LDS
// via global_load_lds. x is register-pipelined at half-chunk granularity:
// A[4]/B[4] float4 per token ping-pong so ~8 dwordx4 loads stay in flight
// continuously per wave (vs ~4 bursty before) and the next chunk's x loads
// are already old when __syncthreads drains vmcnt.
// Compute order: e outer (16, unrolled), i inner (4) -> max 4 live W frags
// per expert. Do NOT reorder to i-outer/e-inner with the pipeline regs live:
// R3/R4 post-mortem showed 64 hoisted ds_reads -> 256+ VGPR -> scratch spill
// (WRITE_SIZE is the sentinel; expect ~3.1 MB here).
// ---------------------------------------------------------------------------
__global__ __launch_bounds__(256, 2) void router_pass_a(
    const float* __restrict__ x, const float* __restrict__ W,
    const float* __restrict__ b, float* __restrict__ out,
    unsigned char* __restrict__ packed, int* __restrict__ gcounts,
    float* __restrict__ idxout, int T)
{
    __shared__ float4 shW4[2 * NE * KC4];   // 2 x 32 KB double buffer

    const int tid  = (int)threadIdx.x;
    const int lane = tid & 63;
    const int wid  = tid >> 6;                    // wave in block
    const int tg   = lane >> 4;                   // token-pair group
    const int kl   = lane & 15;                   // K-lane
    const int tok0 = ((int)blockIdx.x * 4 + wid) * 8 + tg * 2;

    const float4* __restrict__ x4 = (const float4*)x;
    const float4* __restrict__ W4 = (const float4*)W;
    const float4* xp0 = x4 + (size_t)tok0 * D4 + kl;
    const float4* xp1 = xp0 + D4;

    float acc0[NE], acc1[NE];
#pragma unroll
    for (int e = 0; e < NE; ++e) { acc0[e] = 0.f; acc1[e] = 0.f; }

    // stage chunk 0 into buffer 0
#pragma unroll
    for (int j = 0; j < 8; ++j) {
        const int slot = wid * 8 + j;              // 0..31
        const int e = slot >> 1, half = slot & 1;
        load_lds16((const void*)(W4 + (size_t)e * D4 + half * 64 + lane),
                   (void*)(shW4 + slot * 64));
    }

    // folded router_fill: -1 this block's 2 KB slice of expert_indices.
    // Scatter runs after pass_a completes, so ordering is safe.
    if (tid < 128)
        ((float4*)idxout)[(size_t)blockIdx.x * 128 + tid] =
            make_float4(-1.f, -1.f, -1.f, -1.f);

    // x register pipeline: prologue = chunk 0, half 0
    float4 A0[4], A1[4], B0[4], B1[4];
#pragma unroll
    for (int i = 0; i < 4; ++i) { A0[i] = xp0[i << 4]; A1[i] = xp1[i << 4]; }

    for (int kc = 0; kc < NCHUNK; ++kc) {
        __syncthreads();           // stage(kc) + prefetched x landed

        if (kc < NCHUNK - 1) {     // async stage of chunk kc+1 into other buf
            const int nb = ((kc + 1) & 1) * (NE * KC4);
#pragma unroll
            for (int j = 0; j < 8; ++j) {
                const int slot = wid * 8 + j;
                const int e = slot >> 1, half = slot & 1;
                load_lds16((const void*)(W4 + (size_t)e * D4 + (kc + 1) * KC4 +
                                         half * 64 + lane),
                           (void*)(shW4 + nb + slot * 64));
            }
        }

        const float4* bufp = shW4 + (kc & 1) * (NE * KC4) + kl;
        const float4* xb0 = xp0 + kc * KC4;
        const float4* xb1 = xp1 + kc * KC4;

        // prefetch B = (kc, half 1): 8 loads issued back-to-back
#pragma unroll
        for (int i = 0; i < 4; ++i) {
            B0[i] = xb0[64 + (i << 4)];
            B1[i] = xb1[64 + (i << 4)];
        }
        // compute half 0 from A (all LDS reads are base+imm offsets)
#pragma unroll
        for (int e = 0; e < NE; ++e) {
#pragma unroll
            for (int i = 0; i < 4; ++i) {
                float4 w = bufp[e * KC4 + (i << 4)];
                acc0[e] += dot4(A0[i], w);
                acc1[e] += dot4(A1[i], w);
            }
        }
        // prefetch A = (kc+1, half 0) -- in flight across the barrier
        if (kc < NCHUNK - 1) {
#pragma unroll
            for (int i = 0; i < 4; ++i) {
                A0[i] = xb0[KC4 + (i << 4)];
                A1[i] = xb1[KC4 + (i << 4)];
            }
        }
        // compute half 1 from B
#pragma unroll
        for (int e = 0; e < NE; ++e) {
#pragma unroll
            for (int i = 0; i < 4; ++i) {
                float4 w = bufp[e * KC4 + 64 + (i << 4)];
                acc0[e] += dot4(B0[i], w);
                acc1[e] += dot4(B1[i], w);
            }
        }
    }

    // split-exchange within each 16-lane group: acc0[0]/acc1[0] end holding
    // the full sum for expert e == kl.
#pragma unroll
    for (int m = 8; m >= 1; m >>= 1) {
        const bool hi = (kl & m) != 0;
#pragma unroll
        for (int j = 0; j < m; ++j) {
            float s0 = hi ? acc0[j] : acc0[j + m];
            float k0 = hi ? acc0[j + m] : acc0[j];
            acc0[j] = k0 + __shfl_xor(s0, m, 64);
            float s1 = hi ? acc1[j] : acc1[j + m];
            float k1 = hi ? acc1[j + m] : acc1[j];
            acc1[j] = k1 + __shfl_xor(s1, m, 64);
        }
    }

    const float logit0 = acc0[0] + b[kl];
    const float logit1 = acc1[0] + b[kl];
    out[(size_t)tok0 * NE + kl]       = logit0;
    out[(size_t)(tok0 + 1) * NE + kl] = logit1;

    // top-2 merge over the 16-lane group (lower index wins ties), both tokens
    float m1a = logit0; int i1a = kl; float m2a = -__builtin_inff(); int i2a = NE;
    float m1b = logit1; int i1b = kl; float m2b = -__builtin_inff(); int i2b = NE;
#pragma unroll
    for (int m = 1; m <= 8; m <<= 1) {
        {
            float om1 = __shfl_xor(m1a, m, 64); int oi1 = __shfl_xor(i1a, m, 64);
            float om2 = __shfl_xor(m2a, m, 64); int oi2 = __shfl_xor(i2a, m, 64);
            bool aF = (m1a > om1) || (m1a == om1 && i1a < oi1);
            float n1v = aF ? m1a : om1; int n1i = aF ? i1a : oi1;
            float l1v = aF ? om1 : m1a; int l1i = aF ? oi1 : i1a;
            float c2v = aF ? m2a : om2; int c2i = aF ? i2a : oi2;
            bool s = (l1v > c2v) || (l1v == c2v && l1i < c2i);
            m1a = n1v; i1a = n1i; m2a = s ? l1v : c2v; i2a = s ? l1i : c2i;
        }
        {
            float om1 = __shfl_xor(m1b, m, 64); int oi1 = __shfl_xor(i1b, m, 64);
            float om2 = __shfl_xor(m2b, m, 64); int oi2 = __shfl_xor(i2b, m, 64);
            bool aF = (m1b > om1) || (m1b == om1 && i1b < oi1);
            float n1v = aF ? m1b : om1; int n1i = aF ? i1b : oi1;
            float l1v = aF ? om1 : m1b; int l1i = aF ? oi1 : i1b;
            float c2v = aF ? m2b : om2; int c2i = aF ? i2b : oi2;
            bool s = (l1v > c2v) || (l1v == c2v && l1i < c2i);
            m1b = n1v; i1b = n1i; m2b = s ? l1v : c2v; i2b = s ? l1i : c2i;
        }
    }

    float* __restrict__ disp = out + (size_t)T * NE;
    {
        const float q = expf(m2a - m1a);
        const float r1 = 1.f / (1.f + q), r2 = q / (1.f + q);
        disp[(size_t)tok0 * NE + kl] = (kl == i1a) ? r1 : ((kl == i2a) ? r2 : 0.f);
    }
    {
        const float q = expf(m2b - m1b);
        const float r1 = 1.f / (1.f + q), r2 = q / (1.f + q);
        disp[(size_t)(tok0 + 1) * NE + kl] = (kl == i1b) ? r1 : ((kl == i2b) ? r2 : 0.f);
    }

    if (kl == 0) {
        packed[tok0]     = (unsigned char)(i1a | (i2a << 4));
        packed[tok0 + 1] = (unsigned char)(i1b | (i2b << 4));
        int* gc = gcounts + (size_t)(tok0 >> 8) * NE;
        atomicAdd(&gc[i1a], 1);
        atomicAdd(&gc[i2a], 1);
        atomicAdd(&gc[i1b], 1);
        atomicAdd(&gc[i2b], 1);
    }
}

// ---------------------------------------------------------------------------
// Prologue: zero the per-chunk histogram only (the -1 fill of expert_indices
// moved into pass_a). 1 block, 4 KB of writes -- launch-overhead-bound.
// ---------------------------------------------------------------------------
__global__ __launch_bounds__(256) void router_zero(
    int* __restrict__ gcounts, int n4)
{
    int4* g4 = (int4*)gcounts;
    for (int i = (int)threadIdx.x; i < n4; i += 256)
        g4[i] = make_int4(0, 0, 0, 0);
}

// ---------------------------------------------------------------------------
// Scatter: stable compaction. 64 blocks x 256 tokens; 16-way-parallel
// exclusive prefix over gcounts, ballot/popcount intra-block ranking.
// ---------------------------------------------------------------------------
__global__ __launch_bounds__(SCHUNK) void router_scatter(
    const unsigned char* __restrict__ packed, const int* __restrict__ gcounts,
    float* __restrict__ idxout, int T)
{
    const int c    = (int)blockIdx.x;
    const int tid  = (int)threadIdx.x;
    const int lane = tid & 63;
    const int wid  = tid >> 6;              // 0..3
    __shared__ int offs[NE];
    __shared__ int wtot[SCHUNK / 64][NE];

    if (tid < NE) offs[tid] = 0;
    __syncthreads();
    {   // thread (e = tid&15, j = tid>>4) sums gcounts[cc][e], cc = j, j+16, ...
        const int e = tid & 15, j = tid >> 4;
        int s = 0;
        for (int cc = j; cc < c; cc += 16) s += gcounts[cc * NE + e];
        if (s) atomicAdd(&offs[e], s);
    }

    const int t = c * SCHUNK + tid;
    const unsigned p = packed[t];
    const int e1 = (int)(p & 15);
    const int e2 = (int)(p >> 4);

    unsigned long long bal[NE];
#pragma unroll
    for (int ee = 0; ee < NE; ++ee)
        bal[ee] = __ballot((e1 == ee) || (e2 == ee));

    if (lane < NE) wtot[wid][lane] = __popcll(bal[lane]);
    __syncthreads();   // covers offs accumulation + wtot

    const unsigned long long lt = (1ull << lane) - 1ull;
    int r1 = __popcll(bal[e1] & lt);
    int r2 = __popcll(bal[e2] & lt);
    for (int w = 0; w < wid; ++w) { r1 += wtot[w][e1]; r2 += wtot[w][e2]; }

    idxout[(size_t)e1 * T + offs[e1] + r1] = (float)t;
    idxout[(size_t)e2 * T + offs[e2] + r2] = (float)t;
}

extern "C" void kernel_launch(void* const* d_in, const int* in_sizes, int n_in,
                              void* d_out, int out_size, void* d_ws, size_t ws_size,
                              hipStream_t stream)
{
    const float* x = (const float*)d_in[0];
    const float* W = (const float*)d_in[1];
    const float* b = (const float*)d_in[2];
    float* out = (float*)d_out;

    const int T = in_sizes[0] / DDIM;       // 16384 tokens

    unsigned char* packed = (unsigned char*)d_ws;
    int* gcounts = (int*)((char*)d_ws + (((size_t)T + 255) & ~(size_t)255));

    float* idxout = out + (size_t)2 * T * NE;

    // 1) zero histograms (tiny; the -1 fill now lives inside pass_a)
    router_zero<<<1, 256, 0, stream>>>(gcounts, (T / SCHUNK) * NE / 4);

    // 2) logits/top2/dispatch + histogram + (-1)-fill: block = 4 waves = 32 tok
    router_pass_a<<<T / 32, 256, 0, stream>>>(x, W, b, out, packed, gcounts,
                                              idxout, T);

    // 3) stable scatter of token ids
    router_scatter<<<T / SCHUNK, SCHUNK, 0, stream>>>(packed, gcounts, idxout, T);
}

// Round 3
// 405.175 us; speedup vs baseline: 1.4579x; 1.4579x over previous
//
#include <hip/hip_runtime.h>
#include <cstdint>
#include <cstddef>

#define DDIM 4096          // hidden dim
#define D4   1024          // float4 per token row
#define NE   16            // experts
#define KC4  64            // K-chunk in float4 (256 floats) -- halved vs R0
#define NCHUNK 16          // DDIM/4 / KC4
#define SCHUNK 256         // scatter chunk (tokens)

// async 16B global->LDS (lane's data lands at wave-uniform base + lane*16)
__device__ __forceinline__ void load_lds16(const void* g, void* l) {
    __builtin_amdgcn_global_load_lds(
        (const __attribute__((address_space(1))) unsigned int*)g,
        (__attribute__((address_space(3))) unsigned int*)l, 16, 0, 0);
}

__device__ __forceinline__ float dot4(float4 a, float4 w) {
    return a.x * w.x + a.y * w.y + a.z * w.z + a.w * w.w;
}

// ---------------------------------------------------------------------------
// Pass A: logits + top-2 softmax renorm + dispatch + packed pair byte +
// per-256-token-chunk expert histogram + (-1)-fill of this block's slice of
// expert_indices.
// Block = 4 waves = 32 tokens. W staged K-chunk-wise into DOUBLE-BUFFERED LDS
// via global_load_lds. KC4=64 -> 2 x 16 KB LDS (was 2 x 32 KB): LDS cap rises
// from 2 to 5 blocks/CU; VGPR (<=128) allows 4 -> residency doubles to
// 16 waves/CU for latency hiding (R2 showed Occupancy 22% was the limiter
// candidate).
// x loads are INLINE in the unroll-2 i-loop. DO NOT register-pipeline x:
// R2 post-mortem (and R3/R4 before it): >4 in-flight x float4/thread ->
// allocator collapse -> scratch spill. Sentinel: pass_a WRITE_SIZE must be
// ~3.1 MB; R2's spill showed as WRITE_SIZE=590 MB, FETCH +190 MB.
// ---------------------------------------------------------------------------
__global__ __launch_bounds__(256, 2) void router_pass_a(
    const float* __restrict__ x, const float* __restrict__ W,
    const float* __restrict__ b, float* __restrict__ out,
    unsigned char* __restrict__ packed, int* __restrict__ gcounts,
    float* __restrict__ idxout, int T)
{
    __shared__ float4 shW4[2 * NE * KC4];   // 2 x 16 KB double buffer

    const int tid  = (int)threadIdx.x;
    const int lane = tid & 63;
    const int wid  = tid >> 6;                    // wave in block
    const int tg   = lane >> 4;                   // token-pair group
    const int kl   = lane & 15;                   // K-lane
    const int tok0 = ((int)blockIdx.x * 4 + wid) * 8 + tg * 2;

    const float4* __restrict__ x4 = (const float4*)x;
    const float4* __restrict__ W4 = (const float4*)W;
    const float4* xr0 = x4 + (size_t)tok0 * D4;
    const float4* xr1 = xr0 + D4;

    float acc0[NE], acc1[NE];
#pragma unroll
    for (int e = 0; e < NE; ++e) { acc0[e] = 0.f; acc1[e] = 0.f; }

    // stage chunk 0 into buffer 0: one load_lds16 covers one expert's 1 KB
    // chunk (64 lanes x 16 B); wave wid stages experts wid*4 .. wid*4+3.
#pragma unroll
    for (int j = 0; j < 4; ++j) {
        const int e = wid * 4 + j;                 // 0..15
        load_lds16((const void*)(W4 + (size_t)e * D4 + lane),
                   (void*)(shW4 + e * KC4));
    }

    // folded router_fill: -1 this block's 2 KB slice of expert_indices.
    // Scatter runs after pass_a completes, so ordering is safe.
    if (tid < 128)
        ((float4*)idxout)[(size_t)blockIdx.x * 128 + tid] =
            make_float4(-1.f, -1.f, -1.f, -1.f);

    for (int kc = 0; kc < NCHUNK; ++kc) {
        __syncthreads();           // stage(kc) landed (barrier drains vmcnt)

        if (kc < NCHUNK - 1) {     // async stage of chunk kc+1 into other buf
            const int nb = ((kc + 1) & 1) * (NE * KC4);
#pragma unroll
            for (int j = 0; j < 4; ++j) {
                const int e = wid * 4 + j;
                load_lds16((const void*)(W4 + (size_t)e * D4 +
                                         (kc + 1) * KC4 + lane),
                           (void*)(shW4 + nb + e * KC4));
            }
        }

        const float4* bufp = shW4 + (kc & 1) * (NE * KC4) + kl;
        const int base = kc * KC4;
#pragma unroll 2
        for (int i = 0; i < 4; ++i) {
            const int f = base + kl + (i << 4);
            float4 a0 = xr0[f];
            float4 a1 = xr1[f];
            const float4* wrow = bufp + (i << 4);
#pragma unroll
            for (int e = 0; e < NE; ++e) {
                float4 w = wrow[e * KC4];
                acc0[e] += dot4(a0, w);
                acc1[e] += dot4(a1, w);
            }
        }
    }

    // split-exchange within each 16-lane group: acc0[0]/acc1[0] end holding
    // the full sum for expert e == kl.
#pragma unroll
    for (int m = 8; m >= 1; m >>= 1) {
        const bool hi = (kl & m) != 0;
#pragma unroll
        for (int j = 0; j < m; ++j) {
            float s0 = hi ? acc0[j] : acc0[j + m];
            float k0 = hi ? acc0[j + m] : acc0[j];
            acc0[j] = k0 + __shfl_xor(s0, m, 64);
            float s1 = hi ? acc1[j] : acc1[j + m];
            float k1 = hi ? acc1[j + m] : acc1[j];
            acc1[j] = k1 + __shfl_xor(s1, m, 64);
        }
    }

    const float logit0 = acc0[0] + b[kl];
    const float logit1 = acc1[0] + b[kl];
    out[(size_t)tok0 * NE + kl]       = logit0;
    out[(size_t)(tok0 + 1) * NE + kl] = logit1;

    // top-2 merge over the 16-lane group (lower index wins ties), both tokens
    float m1a = logit0; int i1a = kl; float m2a = -__builtin_inff(); int i2a = NE;
    float m1b = logit1; int i1b = kl; float m2b = -__builtin_inff(); int i2b = NE;
#pragma unroll
    for (int m = 1; m <= 8; m <<= 1) {
        {
            float om1 = __shfl_xor(m1a, m, 64); int oi1 = __shfl_xor(i1a, m, 64);
            float om2 = __shfl_xor(m2a, m, 64); int oi2 = __shfl_xor(i2a, m, 64);
            bool aF = (m1a > om1) || (m1a == om1 && i1a < oi1);
            float n1v = aF ? m1a : om1; int n1i = aF ? i1a : oi1;
            float l1v = aF ? om1 : m1a; int l1i = aF ? oi1 : i1a;
            float c2v = aF ? m2a : om2; int c2i = aF ? i2a : oi2;
            bool s = (l1v > c2v) || (l1v == c2v && l1i < c2i);
            m1a = n1v; i1a = n1i; m2a = s ? l1v : c2v; i2a = s ? l1i : c2i;
        }
        {
            float om1 = __shfl_xor(m1b, m, 64); int oi1 = __shfl_xor(i1b, m, 64);
            float om2 = __shfl_xor(m2b, m, 64); int oi2 = __shfl_xor(i2b, m, 64);
            bool aF = (m1b > om1) || (m1b == om1 && i1b < oi1);
            float n1v = aF ? m1b : om1; int n1i = aF ? i1b : oi1;
            float l1v = aF ? om1 : m1b; int l1i = aF ? oi1 : i1b;
            float c2v = aF ? m2b : om2; int c2i = aF ? i2b : oi2;
            bool s = (l1v > c2v) || (l1v == c2v && l1i < c2i);
            m1b = n1v; i1b = n1i; m2b = s ? l1v : c2v; i2b = s ? l1i : c2i;
        }
    }

    float* __restrict__ disp = out + (size_t)T * NE;
    {
        const float q = expf(m2a - m1a);
        const float r1 = 1.f / (1.f + q), r2 = q / (1.f + q);
        disp[(size_t)tok0 * NE + kl] = (kl == i1a) ? r1 : ((kl == i2a) ? r2 : 0.f);
    }
    {
        const float q = expf(m2b - m1b);
        const float r1 = 1.f / (1.f + q), r2 = q / (1.f + q);
        disp[(size_t)(tok0 + 1) * NE + kl] = (kl == i1b) ? r1 : ((kl == i2b) ? r2 : 0.f);
    }

    if (kl == 0) {
        packed[tok0]     = (unsigned char)(i1a | (i2a << 4));
        packed[tok0 + 1] = (unsigned char)(i1b | (i2b << 4));
        int* gc = gcounts + (size_t)(tok0 >> 8) * NE;
        atomicAdd(&gc[i1a], 1);
        atomicAdd(&gc[i2a], 1);
        atomicAdd(&gc[i1b], 1);
        atomicAdd(&gc[i2b], 1);
    }
}

// ---------------------------------------------------------------------------
// Prologue: zero the per-chunk histogram only (the -1 fill of expert_indices
// lives inside pass_a). 1 block, 4 KB of writes -- launch-overhead-bound.
// ---------------------------------------------------------------------------
__global__ __launch_bounds__(256) void router_zero(
    int* __restrict__ gcounts, int n4)
{
    int4* g4 = (int4*)gcounts;
    for (int i = (int)threadIdx.x; i < n4; i += 256)
        g4[i] = make_int4(0, 0, 0, 0);
}

// ---------------------------------------------------------------------------
// Scatter: stable compaction. 64 blocks x 256 tokens; 16-way-parallel
// exclusive prefix over gcounts, ballot/popcount intra-block ranking.
// ---------------------------------------------------------------------------
__global__ __launch_bounds__(SCHUNK) void router_scatter(
    const unsigned char* __restrict__ packed, const int* __restrict__ gcounts,
    float* __restrict__ idxout, int T)
{
    const int c    = (int)blockIdx.x;
    const int tid  = (int)threadIdx.x;
    const int lane = tid & 63;
    const int wid  = tid >> 6;              // 0..3
    __shared__ int offs[NE];
    __shared__ int wtot[SCHUNK / 64][NE];

    if (tid < NE) offs[tid] = 0;
    __syncthreads();
    {   // thread (e = tid&15, j = tid>>4) sums gcounts[cc][e], cc = j, j+16, ...
        const int e = tid & 15, j = tid >> 4;
        int s = 0;
        for (int cc = j; cc < c; cc += 16) s += gcounts[cc * NE + e];
        if (s) atomicAdd(&offs[e], s);
    }

    const int t = c * SCHUNK + tid;
    const unsigned p = packed[t];
    const int e1 = (int)(p & 15);
    const int e2 = (int)(p >> 4);

    unsigned long long bal[NE];
#pragma unroll
    for (int ee = 0; ee < NE; ++ee)
        bal[ee] = __ballot((e1 == ee) || (e2 == ee));

    if (lane < NE) wtot[wid][lane] = __popcll(bal[lane]);
    __syncthreads();   // covers offs accumulation + wtot

    const unsigned long long lt = (1ull << lane) - 1ull;
    int r1 = __popcll(bal[e1] & lt);
    int r2 = __popcll(bal[e2] & lt);
    for (int w = 0; w < wid; ++w) { r1 += wtot[w][e1]; r2 += wtot[w][e2]; }

    idxout[(size_t)e1 * T + offs[e1] + r1] = (float)t;
    idxout[(size_t)e2 * T + offs[e2] + r2] = (float)t;
}

extern "C" void kernel_launch(void* const* d_in, const int* in_sizes, int n_in,
                              void* d_out, int out_size, void* d_ws, size_t ws_size,
                              hipStream_t stream)
{
    const float* x = (const float*)d_in[0];
    const float* W = (const float*)d_in[1];
    const float* b = (const float*)d_in[2];
    float* out = (float*)d_out;

    const int T = in_sizes[0] / DDIM;       // 16384 tokens

    unsigned char* packed = (unsigned char*)d_ws;
    int* gcounts = (int*)((char*)d_ws + (((size_t)T + 255) & ~(size_t)255));

    float* idxout = out + (size_t)2 * T * NE;

    // 1) zero histograms (tiny; the -1 fill lives inside pass_a)
    router_zero<<<1, 256, 0, stream>>>(gcounts, (T / SCHUNK) * NE / 4);

    // 2) logits/top2/dispatch + histogram + (-1)-fill: block = 4 waves = 32 tok
    router_pass_a<<<T / 32, 256, 0, stream>>>(x, W, b, out, packed, gcounts,
                                              idxout, T);

    // 3) stable scatter of token ids
    router_scatter<<<T / SCHUNK, SCHUNK, 0, stream>>>(packed, gcounts, idxout, T);
}

// Round 4
// 371.831 us; speedup vs baseline: 1.5886x; 1.0897x over previous
//
#include <hip/hip_runtime.h>
#include <cstdint>
#include <cstddef>

#define DDIM 4096          // hidden dim
#define D4   1024          // float4 per token row
#define NE   16            // experts
#define KC4  128           // K-chunk in float4 (512 floats)
#define NCHUNK 8           // DDIM / 512
#define SCHUNK 256         // scatter chunk (tokens)

// async 16B global->LDS (lane's data lands at wave-uniform base + lane*16)
__device__ __forceinline__ void load_lds16(const void* g, void* l) {
    __builtin_amdgcn_global_load_lds(
        (const __attribute__((address_space(1))) unsigned int*)g,
        (__attribute__((address_space(3))) unsigned int*)l, 16, 0, 0);
}

__device__ __forceinline__ float dot4(float4 a, float4 w) {
    return a.x * w.x + a.y * w.y + a.z * w.z + a.w * w.w;
}

// ---------------------------------------------------------------------------
// Pass A: logits + top-2 softmax renorm + dispatch + packed pair byte +
// per-256-token-chunk expert histogram + (-1)-fill of this block's 2 KB slice
// of expert_indices (folded; hides under the x stream).
// Block = 4 waves = 32 tokens. W staged K-chunk-wise into DOUBLE-BUFFERED LDS
// via global_load_lds (KC4=128, 2 x 32 KB). This is the proven 372-us loop.
// LESSONS (counter-backed, do NOT retry):
//  - R2: half-chunk x register pipeline (A[4]/B[4] ping-pong) -> allocator
//    collapse, scratch spill: WRITE_SIZE 3 MB -> 590 MB, dur 48 -> 327 us.
//    >4 in-flight x float4/thread is fatal. Keep a0/a1 INLINE.
//  - R3: KC4=64 (32 KB LDS) -> grid is 512 blocks = 2 blocks/CU ANYWAY
//    (grid-limited, not LDS-limited); 2x barriers bought nothing, cost
//    ~30 us. Occupancy is NOT the BW limiter (fills hit 6.8 TB/s at 10%).
// ---------------------------------------------------------------------------
__global__ __launch_bounds__(256, 2) void router_pass_a(
    const float* __restrict__ x, const float* __restrict__ W,
    const float* __restrict__ b, float* __restrict__ out,
    unsigned char* __restrict__ packed, int* __restrict__ gcounts,
    float* __restrict__ idxout, int T)
{
    __shared__ float4 shW4[2 * NE * KC4];   // 2 x 32 KB double buffer

    const int tid  = (int)threadIdx.x;
    const int lane = tid & 63;
    const int wid  = tid >> 6;                    // wave in block
    const int tg   = lane >> 4;                   // token-pair group
    const int kl   = lane & 15;                   // K-lane
    const int tok0 = ((int)blockIdx.x * 4 + wid) * 8 + tg * 2;

    const float4* __restrict__ x4 = (const float4*)x;
    const float4* __restrict__ W4 = (const float4*)W;
    const float4* xr0 = x4 + (size_t)tok0 * D4;
    const float4* xr1 = xr0 + D4;

    float acc0[NE], acc1[NE];
#pragma unroll
    for (int e = 0; e < NE; ++e) { acc0[e] = 0.f; acc1[e] = 0.f; }

    // stage chunk 0 into buffer 0
#pragma unroll
    for (int j = 0; j < 8; ++j) {
        const int slot = wid * 8 + j;              // 0..31
        const int e = slot >> 1, half = slot & 1;
        load_lds16((const void*)(W4 + (size_t)e * D4 + half * 64 + lane),
                   (void*)(shW4 + slot * 64));
    }

    // folded router_fill: -1 this block's 2 KB slice of expert_indices.
    // Scatter runs after pass_a completes (same stream), so ordering is safe.
    if (tid < 128)
        ((float4*)idxout)[(size_t)blockIdx.x * 128 + tid] =
            make_float4(-1.f, -1.f, -1.f, -1.f);

    for (int kc = 0; kc < NCHUNK; ++kc) {
        __syncthreads();           // stage(kc) landed (barrier drains vmcnt)

        if (kc < NCHUNK - 1) {     // async stage of chunk kc+1 into other buf
            const int nb = ((kc + 1) & 1) * (NE * KC4);
#pragma unroll
            for (int j = 0; j < 8; ++j) {
                const int slot = wid * 8 + j;
                const int e = slot >> 1, half = slot & 1;
                load_lds16((const void*)(W4 + (size_t)e * D4 + (kc + 1) * KC4 +
                                         half * 64 + lane),
                           (void*)(shW4 + nb + slot * 64));
            }
        }

        const float4* bufp = shW4 + (kc & 1) * (NE * KC4);
        const int base = kc * KC4;
#pragma unroll 2
        for (int i = 0; i < 8; ++i) {
            const int f = base + kl + (i << 4);
            float4 a0 = xr0[f];
            float4 a1 = xr1[f];
            const float4* wrow = bufp + kl + (i << 4);
#pragma unroll
            for (int e = 0; e < NE; ++e) {
                float4 w = wrow[e * KC4];
                acc0[e] += dot4(a0, w);
                acc1[e] += dot4(a1, w);
            }
        }
    }

    // split-exchange within each 16-lane group: acc0[0]/acc1[0] end holding
    // the full sum for expert e == kl.
#pragma unroll
    for (int m = 8; m >= 1; m >>= 1) {
        const bool hi = (kl & m) != 0;
#pragma unroll
        for (int j = 0; j < m; ++j) {
            float s0 = hi ? acc0[j] : acc0[j + m];
            float k0 = hi ? acc0[j + m] : acc0[j];
            acc0[j] = k0 + __shfl_xor(s0, m, 64);
            float s1 = hi ? acc1[j] : acc1[j + m];
            float k1 = hi ? acc1[j + m] : acc1[j];
            acc1[j] = k1 + __shfl_xor(s1, m, 64);
        }
    }

    const float logit0 = acc0[0] + b[kl];
    const float logit1 = acc1[0] + b[kl];
    out[(size_t)tok0 * NE + kl]       = logit0;
    out[(size_t)(tok0 + 1) * NE + kl] = logit1;

    // top-2 merge over the 16-lane group (lower index wins ties), both tokens
    float m1a = logit0; int i1a = kl; float m2a = -__builtin_inff(); int i2a = NE;
    float m1b = logit1; int i1b = kl; float m2b = -__builtin_inff(); int i2b = NE;
#pragma unroll
    for (int m = 1; m <= 8; m <<= 1) {
        {
            float om1 = __shfl_xor(m1a, m, 64); int oi1 = __shfl_xor(i1a, m, 64);
            float om2 = __shfl_xor(m2a, m, 64); int oi2 = __shfl_xor(i2a, m, 64);
            bool aF = (m1a > om1) || (m1a == om1 && i1a < oi1);
            float n1v = aF ? m1a : om1; int n1i = aF ? i1a : oi1;
            float l1v = aF ? om1 : m1a; int l1i = aF ? oi1 : i1a;
            float c2v = aF ? m2a : om2; int c2i = aF ? i2a : oi2;
            bool s = (l1v > c2v) || (l1v == c2v && l1i < c2i);
            m1a = n1v; i1a = n1i; m2a = s ? l1v : c2v; i2a = s ? l1i : c2i;
        }
        {
            float om1 = __shfl_xor(m1b, m, 64); int oi1 = __shfl_xor(i1b, m, 64);
            float om2 = __shfl_xor(m2b, m, 64); int oi2 = __shfl_xor(i2b, m, 64);
            bool aF = (m1b > om1) || (m1b == om1 && i1b < oi1);
            float n1v = aF ? m1b : om1; int n1i = aF ? i1b : oi1;
            float l1v = aF ? om1 : m1b; int l1i = aF ? oi1 : i1b;
            float c2v = aF ? m2b : om2; int c2i = aF ? i2b : oi2;
            bool s = (l1v > c2v) || (l1v == c2v && l1i < c2i);
            m1b = n1v; i1b = n1i; m2b = s ? l1v : c2v; i2b = s ? l1i : c2i;
        }
    }

    float* __restrict__ disp = out + (size_t)T * NE;
    {
        const float q = expf(m2a - m1a);
        const float r1 = 1.f / (1.f + q), r2 = q / (1.f + q);
        disp[(size_t)tok0 * NE + kl] = (kl == i1a) ? r1 : ((kl == i2a) ? r2 : 0.f);
    }
    {
        const float q = expf(m2b - m1b);
        const float r1 = 1.f / (1.f + q), r2 = q / (1.f + q);
        disp[(size_t)(tok0 + 1) * NE + kl] = (kl == i1b) ? r1 : ((kl == i2b) ? r2 : 0.f);
    }

    if (kl == 0) {
        packed[tok0]     = (unsigned char)(i1a | (i2a << 4));
        packed[tok0 + 1] = (unsigned char)(i1b | (i2b << 4));
        int* gc = gcounts + (size_t)(tok0 >> 8) * NE;
        atomicAdd(&gc[i1a], 1);
        atomicAdd(&gc[i2a], 1);
        atomicAdd(&gc[i1b], 1);
        atomicAdd(&gc[i2b], 1);
    }
}

// ---------------------------------------------------------------------------
// Prologue: zero the per-chunk histogram only (the -1 fill of expert_indices
// lives inside pass_a). 1 block, 4 KB of writes -- launch-overhead-bound.
// ---------------------------------------------------------------------------
__global__ __launch_bounds__(256) void router_zero(
    int* __restrict__ gcounts, int n4)
{
    int4* g4 = (int4*)gcounts;
    for (int i = (int)threadIdx.x; i < n4; i += 256)
        g4[i] = make_int4(0, 0, 0, 0);
}

// ---------------------------------------------------------------------------
// Scatter: stable compaction. 64 blocks x 256 tokens; 16-way-parallel
// exclusive prefix over gcounts, ballot/popcount intra-block ranking.
// ---------------------------------------------------------------------------
__global__ __launch_bounds__(SCHUNK) void router_scatter(
    const unsigned char* __restrict__ packed, const int* __restrict__ gcounts,
    float* __restrict__ idxout, int T)
{
    const int c    = (int)blockIdx.x;
    const int tid  = (int)threadIdx.x;
    const int lane = tid & 63;
    const int wid  = tid >> 6;              // 0..3
    __shared__ int offs[NE];
    __shared__ int wtot[SCHUNK / 64][NE];

    if (tid < NE) offs[tid] = 0;
    __syncthreads();
    {   // thread (e = tid&15, j = tid>>4) sums gcounts[cc][e], cc = j, j+16, ...
        const int e = tid & 15, j = tid >> 4;
        int s = 0;
        for (int cc = j; cc < c; cc += 16) s += gcounts[cc * NE + e];
        if (s) atomicAdd(&offs[e], s);
    }

    const int t = c * SCHUNK + tid;
    const unsigned p = packed[t];
    const int e1 = (int)(p & 15);
    const int e2 = (int)(p >> 4);

    unsigned long long bal[NE];
#pragma unroll
    for (int ee = 0; ee < NE; ++ee)
        bal[ee] = __ballot((e1 == ee) || (e2 == ee));

    if (lane < NE) wtot[wid][lane] = __popcll(bal[lane]);
    __syncthreads();   // covers offs accumulation + wtot

    const unsigned long long lt = (1ull << lane) - 1ull;
    int r1 = __popcll(bal[e1] & lt);
    int r2 = __popcll(bal[e2] & lt);
    for (int w = 0; w < wid; ++w) { r1 += wtot[w][e1]; r2 += wtot[w][e2]; }

    idxout[(size_t)e1 * T + offs[e1] + r1] = (float)t;
    idxout[(size_t)e2 * T + offs[e2] + r2] = (float)t;
}

extern "C" void kernel_launch(void* const* d_in, const int* in_sizes, int n_in,
                              void* d_out, int out_size, void* d_ws, size_t ws_size,
                              hipStream_t stream)
{
    const float* x = (const float*)d_in[0];
    const float* W = (const float*)d_in[1];
    const float* b = (const float*)d_in[2];
    float* out = (float*)d_out;

    const int T = in_sizes[0] / DDIM;       // 16384 tokens

    unsigned char* packed = (unsigned char*)d_ws;
    int* gcounts = (int*)((char*)d_ws + (((size_t)T + 255) & ~(size_t)255));

    float* idxout = out + (size_t)2 * T * NE;

    // 1) zero histograms (tiny; the -1 fill lives inside pass_a)
    router_zero<<<1, 256, 0, stream>>>(gcounts, (T / SCHUNK) * NE / 4);

    // 2) logits/top2/dispatch + histogram + (-1)-fill: block = 4 waves = 32 tok
    router_pass_a<<<T / 32, 256, 0, stream>>>(x, W, b, out, packed, gcounts,
                                              idxout, T);

    // 3) stable scatter of token ids
    router_scatter<<<T / SCHUNK, SCHUNK, 0, stream>>>(packed, gcounts, idxout, T);
}